// Round 10
// baseline (493.540 us; speedup 1.0000x reference)
//
#include <hip/hip_runtime.h>
#include <cstdint>

typedef __attribute__((ext_vector_type(8))) short bf16x8;
typedef __attribute__((ext_vector_type(4))) float f32x4;
typedef unsigned short u16;

#define RD(p) (*(const bf16x8*)(p))

__device__ inline u16 f2bf(float f) {
  union { float f; unsigned int u; } v; v.f = f;
  unsigned int u = v.u;
  unsigned int r = (u + 0x7fffu + ((u >> 16) & 1u)) >> 16;
  return (u16)r;
}

__device__ inline void gload_lds16(const u16* g, u16* l) {
  __builtin_amdgcn_global_load_lds(
      (const __attribute__((address_space(1))) void*)g,
      (__attribute__((address_space(3))) void*)l, 16, 0, 0);
}

// ---- conversions ----
__global__ void cvt_f32_bf16(const float* __restrict__ src, u16* __restrict__ dst, int n8) {
  int i = blockIdx.x * blockDim.x + threadIdx.x;
  int stride = gridDim.x * blockDim.x;
  for (; i < n8; i += stride) {
    const float4* s = (const float4*)(src + (size_t)i * 8);
    float4 a = s[0], b = s[1];
    union { u16 h[8]; uint4 v; } o;
    o.h[0] = f2bf(a.x); o.h[1] = f2bf(a.y); o.h[2] = f2bf(a.z); o.h[3] = f2bf(a.w);
    o.h[4] = f2bf(b.x); o.h[5] = f2bf(b.y); o.h[6] = f2bf(b.z); o.h[7] = f2bf(b.w);
    *(uint4*)(dst + (size_t)i * 8) = o.v;
  }
}

__global__ void cvt_w3x(const float* __restrict__ s0, const float* __restrict__ s1,
                        const float* __restrict__ s2, u16* __restrict__ d0,
                        u16* __restrict__ d1, u16* __restrict__ d2) {
  const int n8 = 524288;
  int i = blockIdx.x * blockDim.x + threadIdx.x;
  int stride = gridDim.x * blockDim.x;
  for (; i < 3 * n8; i += stride) {
    int seg = i / n8;
    int j = i - seg * n8;
    const float* src = (seg == 0) ? s0 : (seg == 1) ? s1 : s2;
    u16* dst = (seg == 0) ? d0 : (seg == 1) ? d1 : d2;
    const float4* s = (const float4*)(src + (size_t)j * 8);
    float4 a = s[0], b = s[1];
    union { u16 h[8]; uint4 v; } o;
    o.h[0] = f2bf(a.x); o.h[1] = f2bf(a.y); o.h[2] = f2bf(a.z); o.h[3] = f2bf(a.w);
    o.h[4] = f2bf(b.x); o.h[5] = f2bf(b.y); o.h[6] = f2bf(b.z); o.h[7] = f2bf(b.w);
    *(uint4*)(dst + (size_t)j * 8) = o.v;
  }
}

// ==================== fused gate+up, 1-phase 256x128 tile, TPB=4, swapped MFMA ====================
__launch_bounds__(512, 2)
__global__ void gemm_gateup1(const u16* __restrict__ xb, const u16* __restrict__ w1b,
                             const u16* __restrict__ w3b, u16* __restrict__ hout) {
  constexpr int NT = 8;          // K-tiles per output tile (K=512)
  constexpr int TPB = 4;         // output tiles per block (nt dir, shared A panel)
  constexpr int TOT = NT * TPB;  // 32 flat K-steps
  __shared__ __attribute__((aligned(16))) u16 lA[2][256 * 64];
  __shared__ __attribute__((aligned(16))) u16 lB[2][2][128 * 64];

  int bid = blockIdx.x;
  int sw = (bid & 7) * 128 + (bid >> 3);   // 1024 wg, bijective
  int nblk = sw >> 8;
  int rem = sw & 255;
  int mt = rem >> 2, ntg = rem & 3;

  int tid = threadIdx.x, w = tid >> 6, ln = tid & 63;
  int wr = w >> 1, wc = w & 1;
  int l15 = ln & 15, l4 = ln >> 4;
  int lr = ln >> 3, ln8 = ln & 7;

  // read offsets (bytes); 3-bit XOR swizzle
  int cx0 = ((l4 ^ (l15 & 7)) << 4);
  int cx1 = (((4 + l4) ^ (l15 & 7)) << 4);
  int aOff0 = (wr * 64 + l15) * 128 + cx0;
  int aOff1 = (wr * 64 + l15) * 128 + cx1;
  int bOff0 = (wc * 64 + l15) * 128 + cx0;
  int bOff1 = (wc * 64 + l15) * 128 + cx1;

  // stage constants
  int u0t = w * 8, u1t = 64 + w * 8;
  int rbA0 = ((u0t >> 5) << 6) + (u0t & 31);
  int rbA1 = ((u1t >> 5) << 6) + (u1t & 31);
  int dA0 = rbA0 * 128, dA1 = rbA1 * 128;
  int dB0 = u0t * 128, dB1 = u1t * 128;
  int gaA0 = rbA0 * 2048, gaA1 = rbA1 * 2048;
  int gaB0 = u0t * 512, gaB1 = u1t * 512;
  int swzg = (ln8 ^ lr) << 3;

  const u16* gA  = xb  + (size_t)(mt * 256) * 2048 + nblk * 512 + lr * 2048 + swzg;
  const u16* gB1 = w1b + (size_t)nblk * (2048 * 512) + (size_t)(ntg * 512) * 512 + lr * 512 + swzg;
  const u16* gB3 = w3b + (size_t)nblk * (2048 * 512) + (size_t)(ntg * 512) * 512 + lr * 512 + swzg;

  #define OFFA(s) (((s) & 7) * 64)
  #define OFFB(s) ((((s) >> 3) << 16) + (((s) & 7) * 64))

  f32x4 acc1[4][4], acc3[4][4];
#pragma unroll
  for (int i = 0; i < 4; i++)
#pragma unroll
    for (int j = 0; j < 4; j++) {
      acc1[i][j] = (f32x4){0.f, 0.f, 0.f, 0.f};
      acc3[i][j] = (f32x4){0.f, 0.f, 0.f, 0.f};
    }

  // prologue: stage s=0 -> buf0 (A x4, B1 x2, B3 x2)
  gload_lds16(gA + gaA0,          (u16*)((char*)lA + dA0));
  gload_lds16(gA + gaA1,          (u16*)((char*)lA + dA1));
  gload_lds16(gA + gaA0 + 65536,  (u16*)((char*)lA + dA0 + 4096));
  gload_lds16(gA + gaA1 + 65536,  (u16*)((char*)lA + dA1 + 4096));
  gload_lds16(gB1 + gaB0,         (u16*)((char*)lB + dB0));
  gload_lds16(gB1 + gaB1,         (u16*)((char*)lB + dB1));
  gload_lds16(gB3 + gaB0,         (u16*)((char*)lB + 16384 + dB0));
  gload_lds16(gB3 + gaB1,         (u16*)((char*)lB + 16384 + dB1));
  asm volatile("s_waitcnt vmcnt(0)" ::: "memory");
  __builtin_amdgcn_s_barrier();

  int sCur = 0, sNxt = 32768;
  bf16x8 aT[4][2], b1[4][2], b3[4][2];

  for (int kt = 0; kt < TOT; ++kt) {
    const char* pA0 = (const char*)lA + (sCur + aOff0);
    const char* pA1 = (const char*)lA + (sCur + aOff1);
    const char* pB0 = (const char*)lB + (sCur + bOff0);
    const char* pB1p = (const char*)lB + (sCur + bOff1);
    int s1 = kt + 1;
    int oA1 = OFFA(s1), oB1o = OFFB(s1);
    bool q1 = (s1 < TOT);

    // ---- reads: A (8) + B1 (8) + B3 (8)
#pragma unroll
    for (int f = 0; f < 2; ++f) {
      aT[f][0] = RD(pA0 + f * 2048);            aT[f][1] = RD(pA1 + f * 2048);
      aT[2 + f][0] = RD(pA0 + 4096 + f * 2048); aT[2 + f][1] = RD(pA1 + 4096 + f * 2048);
    }
#pragma unroll
    for (int g = 0; g < 4; ++g) {
      b1[g][0] = RD(pB0 + g * 2048);         b1[g][1] = RD(pB1p + g * 2048);
      b3[g][0] = RD(pB0 + 16384 + g * 2048); b3[g][1] = RD(pB1p + 16384 + g * 2048);
    }
    // ---- stage everything for s+1 into the OTHER buffer (race-free dbuf)
    if (q1) {
      gload_lds16(gA + oA1 + gaA0,          (u16*)((char*)lA + sNxt + dA0));
      gload_lds16(gA + oA1 + gaA1,          (u16*)((char*)lA + sNxt + dA1));
      gload_lds16(gA + oA1 + gaA0 + 65536,  (u16*)((char*)lA + sNxt + dA0 + 4096));
      gload_lds16(gA + oA1 + gaA1 + 65536,  (u16*)((char*)lA + sNxt + dA1 + 4096));
      gload_lds16(gB1 + oB1o + gaB0,        (u16*)((char*)lB + sNxt + dB0));
      gload_lds16(gB1 + oB1o + gaB1,        (u16*)((char*)lB + sNxt + dB1));
      gload_lds16(gB3 + oB1o + gaB0,        (u16*)((char*)lB + sNxt + 16384 + dB0));
      gload_lds16(gB3 + oB1o + gaB1,        (u16*)((char*)lB + sNxt + 16384 + dB1));
    }
    __builtin_amdgcn_s_barrier();
    asm volatile("s_waitcnt lgkmcnt(0)" ::: "memory");
    __builtin_amdgcn_s_setprio(1);
#pragma unroll
    for (int f = 0; f < 4; ++f)
#pragma unroll
      for (int g = 0; g < 4; ++g)
#pragma unroll
        for (int ks = 0; ks < 2; ++ks) {
          acc1[f][g] = __builtin_amdgcn_mfma_f32_16x16x32_bf16(b1[g][ks], aT[f][ks], acc1[f][g], 0, 0, 0);
          acc3[f][g] = __builtin_amdgcn_mfma_f32_16x16x32_bf16(b3[g][ks], aT[f][ks], acc3[f][g], 0, 0, 0);
        }
    __builtin_amdgcn_s_setprio(0);
    asm volatile("s_waitcnt vmcnt(0)" ::: "memory");
    __builtin_amdgcn_s_barrier();
    sCur ^= 32768; sNxt ^= 32768;

    // ---- per-tile epilogue (burst of packed 8B stores; retire under next step)
    if ((kt & 7) == 7) {
      int nt = ntg * 4 + (kt >> 3);
      u16* Hb = hout + (size_t)(mt * 256 + wr * 64) * 8192 + nblk * 2048 + nt * 128 + wc * 64;
#pragma unroll
      for (int f = 0; f < 4; ++f) {
        u16* Hrow = Hb + (size_t)(f * 16 + l15) * 8192 + l4 * 4;
#pragma unroll
        for (int g = 0; g < 4; ++g) {
          union { u16 h[4]; uint2 v; } o;
#pragma unroll
          for (int r = 0; r < 4; ++r) {
            float gate = acc1[f][g][r];
            float up = acc3[f][g][r];
            float s = gate * __builtin_amdgcn_rcpf(1.f + __expf(-gate));
            o.h[r] = f2bf(s * up);
          }
          *(uint2*)(Hrow + g * 16) = o.v;
        }
      }
#pragma unroll
      for (int i = 0; i < 4; i++)
#pragma unroll
        for (int j = 0; j < 4; j++) {
          acc1[i][j] = (f32x4){0.f, 0.f, 0.f, 0.f};
          acc3[i][j] = (f32x4){0.f, 0.f, 0.f, 0.f};
        }
    }
  }
  #undef OFFA
  #undef OFFB
}

// ==================== down projection, 1-phase 256x256 tile, swapped MFMA ====================
__launch_bounds__(512, 2)
__global__ void gemm_down1(const u16* __restrict__ hmat, const u16* __restrict__ w2b,
                           float* __restrict__ out) {
  constexpr int NT = 32;  // K = 2048 / 64
  __shared__ __attribute__((aligned(16))) u16 lA[2][256 * 64];
  __shared__ __attribute__((aligned(16))) u16 lB[2][256 * 64];

  int bid = blockIdx.x;
  int sw = (bid & 7) * 64 + (bid >> 3);   // 512 wg, bijective
  int nblk = sw >> 7;
  int rem = sw & 127;
  int mt = rem >> 1, nt = rem & 1;

  int tid = threadIdx.x, w = tid >> 6, ln = tid & 63;
  int mi = w >> 2, nj = w & 3;
  int l15 = ln & 15, l4 = ln >> 4;
  int lr = ln >> 3, ln8 = ln & 7;

  int cx0 = ((l4 ^ (l15 & 7)) << 4);
  int cx1 = (((4 + l4) ^ (l15 & 7)) << 4);
  int aOff0 = (mi * 128 + l15) * 128 + cx0;
  int aOff1 = (mi * 128 + l15) * 128 + cx1;
  int bOff0 = (nj * 64 + l15) * 128 + cx0;
  int bOff1 = (nj * 64 + l15) * 128 + cx1;

  int u0t = w * 8, u1t = 64 + w * 8;
  int dA0 = u0t * 128, dA1 = (64 + u1t) * 128;
  int rbB0 = ((u0t >> 5) << 6) + (u0t & 31);
  int rbB1 = ((u1t >> 5) << 6) + (u1t & 31);
  int dB0 = rbB0 * 128, dB1 = rbB1 * 128;
  int gaA0 = u0t * 8192, gaA1 = (64 + u1t) * 8192;
  int gaB0 = rbB0 * 2048, gaB1 = rbB1 * 2048;
  int swzg = (ln8 ^ lr) << 3;

  const u16* gA = hmat + (size_t)(mt * 256) * 8192 + nblk * 2048 + lr * 8192 + swzg;
  const u16* gB = w2b + (size_t)nblk * (512 * 2048) + (size_t)(nt * 256) * 2048 + lr * 2048 + swzg;

  f32x4 acc[8][4];
#pragma unroll
  for (int i = 0; i < 8; i++)
#pragma unroll
    for (int j = 0; j < 4; j++) acc[i][j] = (f32x4){0.f, 0.f, 0.f, 0.f};

  // prologue: stage k=0 -> buf0 (A x4, B x4)
  gload_lds16(gA + gaA0,            (u16*)((char*)lA + dA0));
  gload_lds16(gA + gaA1,            (u16*)((char*)lA + dA1));
  gload_lds16(gA + gaA0 + 524288,   (u16*)((char*)lA + dA0 + 8192));
  gload_lds16(gA + gaA1 + 524288,   (u16*)((char*)lA + dA1 + 8192));
  gload_lds16(gB + gaB0,            (u16*)((char*)lB + dB0));
  gload_lds16(gB + gaB1,            (u16*)((char*)lB + dB1));
  gload_lds16(gB + gaB0 + 65536,    (u16*)((char*)lB + dB0 + 4096));
  gload_lds16(gB + gaB1 + 65536,    (u16*)((char*)lB + dB1 + 4096));
  asm volatile("s_waitcnt vmcnt(0)" ::: "memory");
  __builtin_amdgcn_s_barrier();

  int sCur = 0, sNxt = 32768;
  bf16x8 aF[8][2], bLo[2][2], bHi[2][2];

  for (int kt = 0; kt < NT; ++kt) {
    const char* pA0 = (const char*)lA + (sCur + aOff0);
    const char* pA1 = (const char*)lA + (sCur + aOff1);
    const char* pB0 = (const char*)lB + (sCur + bOff0);
    const char* pB1p = (const char*)lB + (sCur + bOff1);
    int kO1 = (kt + 1) * 64;
    bool q1 = (kt + 1 < NT);

    // ---- reads: A f0-7 (16) + B lo/hi (8)
#pragma unroll
    for (int f = 0; f < 4; ++f) {
      aF[f][0] = RD(pA0 + f * 2048);            aF[f][1] = RD(pA1 + f * 2048);
      aF[4 + f][0] = RD(pA0 + 8192 + f * 2048); aF[4 + f][1] = RD(pA1 + 8192 + f * 2048);
    }
#pragma unroll
    for (int g = 0; g < 2; ++g) {
      bLo[g][0] = RD(pB0 + g * 2048);        bLo[g][1] = RD(pB1p + g * 2048);
      bHi[g][0] = RD(pB0 + 4096 + g * 2048); bHi[g][1] = RD(pB1p + 4096 + g * 2048);
    }
    // ---- stage everything for kt+1 into the OTHER buffer
    if (q1) {
      gload_lds16(gA + kO1 + gaA0,          (u16*)((char*)lA + sNxt + dA0));
      gload_lds16(gA + kO1 + gaA1,          (u16*)((char*)lA + sNxt + dA1));
      gload_lds16(gA + kO1 + gaA0 + 524288, (u16*)((char*)lA + sNxt + dA0 + 8192));
      gload_lds16(gA + kO1 + gaA1 + 524288, (u16*)((char*)lA + sNxt + dA1 + 8192));
      gload_lds16(gB + kO1 + gaB0,          (u16*)((char*)lB + sNxt + dB0));
      gload_lds16(gB + kO1 + gaB1,          (u16*)((char*)lB + sNxt + dB1));
      gload_lds16(gB + kO1 + gaB0 + 65536,  (u16*)((char*)lB + sNxt + dB0 + 4096));
      gload_lds16(gB + kO1 + gaB1 + 65536,  (u16*)((char*)lB + sNxt + dB1 + 4096));
    }
    __builtin_amdgcn_s_barrier();
    asm volatile("s_waitcnt lgkmcnt(0)" ::: "memory");
    __builtin_amdgcn_s_setprio(1);
#pragma unroll
    for (int f = 0; f < 8; ++f)
#pragma unroll
      for (int g = 0; g < 2; ++g)
#pragma unroll
        for (int ks = 0; ks < 2; ++ks) {
          acc[f][g]     = __builtin_amdgcn_mfma_f32_16x16x32_bf16(bLo[g][ks], aF[f][ks], acc[f][g], 0, 0, 0);
          acc[f][2 + g] = __builtin_amdgcn_mfma_f32_16x16x32_bf16(bHi[g][ks], aF[f][ks], acc[f][2 + g], 0, 0, 0);
        }
    __builtin_amdgcn_s_setprio(0);
    asm volatile("s_waitcnt vmcnt(0)" ::: "memory");
    __builtin_amdgcn_s_barrier();
    sCur ^= 32768; sNxt ^= 32768;
  }

  // epilogue: swapped layout — token = f*16 + l15, d = g*16 + l4*4 + r; 16B stores
  float* Ob = out + (size_t)(mt * 256 + mi * 128) * 2048 + nblk * 512 + nt * 256 + nj * 64;
#pragma unroll
  for (int f = 0; f < 8; ++f) {
    float* Orow = Ob + (size_t)(f * 16 + l15) * 2048 + l4 * 4;
#pragma unroll
    for (int g = 0; g < 4; ++g)
      *(f32x4*)(Orow + g * 16) = acc[f][g];
  }
}

extern "C" void kernel_launch(void* const* d_in, const int* in_sizes, int n_in,
                              void* d_out, int out_size, void* d_ws, size_t ws_size,
                              hipStream_t stream) {
  const float* x  = (const float*)d_in[0];
  const float* w1 = (const float*)d_in[1];
  const float* w3 = (const float*)d_in[2];
  const float* w2 = (const float*)d_in[3];

  char* ws = (char*)d_ws;
  u16* xb  = (u16*)(ws);                 // 64 MiB
  u16* w1b = (u16*)(ws + 67108864);      // 8 MiB
  u16* w3b = (u16*)(ws + 75497472);
  u16* w2b = (u16*)(ws + 83886080);
  u16* h   = (u16*)(ws + 92274688);      // 256 MiB

  cvt_w3x<<<2048, 256, 0, stream>>>(w1, w3, w2, w1b, w3b, w2b);
  cvt_f32_bf16<<<2048, 256, 0, stream>>>(x, xb, 33554432 / 8);

  gemm_gateup1<<<1024, 512, 0, stream>>>(xb, w1b, w3b, h);
  gemm_down1<<<512, 512, 0, stream>>>(h, w2b, (float*)d_out);
}